// Round 13
// baseline (434.897 us; speedup 1.0000x reference)
//
#include <hip/hip_runtime.h>
#include <math.h>

#define Bn 4096
#define Dn 64
#define Kn 256
#define DKn 16384
#define SLAB ((size_t)262144)   // per-k slab in xh: Bn*Dn

typedef __attribute__((ext_vector_type(8))) short bf16x8;
typedef __attribute__((ext_vector_type(4))) float f32x4;
typedef unsigned short u16;
typedef unsigned int u32;

__device__ __forceinline__ float bf2f(u16 u) {
  return __uint_as_float(((u32)u) << 16);
}
__device__ __forceinline__ u16 f2bf(float f) {  // RNE
  u32 x = __float_as_uint(f);
  u32 r = x + 0x7fffu + ((x >> 16) & 1u);
  return (u16)(r >> 16);
}
// wave-internal LDS ordering fence (rule #18): stops compiler reordering.
__device__ __forceinline__ void wave_lds_fence() {
  asm volatile("s_waitcnt lgkmcnt(0)" ::: "memory");
  __builtin_amdgcn_sched_barrier(0);
}

// ---- K1: x[B,D,K] fp32 -> xh[k][b][d] bf16; double-buffered, 1 barrier/iter
__global__ __launch_bounds__(256) void k1_transpose(
    const float* __restrict__ x, u16* __restrict__ xh) {
  __shared__ float tf[2][64][65];
  const int b0 = blockIdx.x * 8;
  const int k0 = blockIdx.y * 64;
  const int t = threadIdx.x;
  const int kq = t & 15, dsub = t >> 4;
  const int dq = t & 7, kr = t >> 3;

  float4 rv[4];
#pragma unroll
  for (int i = 0; i < 4; ++i)
    rv[i] = *(const float4*)&x[(size_t)b0 * DKn + (size_t)(dsub + 16 * i) * Kn + k0 + 4 * kq];
#pragma unroll
  for (int i = 0; i < 4; ++i) {
    const int d = dsub + 16 * i;
    tf[0][4 * kq + 0][d] = rv[i].x;
    tf[0][4 * kq + 1][d] = rv[i].y;
    tf[0][4 * kq + 2][d] = rv[i].z;
    tf[0][4 * kq + 3][d] = rv[i].w;
  }
  __syncthreads();

  for (int bb = 0; bb < 8; ++bb) {
    const int cur = bb & 1;
    if (bb < 7) {
#pragma unroll
      for (int i = 0; i < 4; ++i)
        rv[i] = *(const float4*)&x[(size_t)(b0 + bb + 1) * DKn +
                                   (size_t)(dsub + 16 * i) * Kn + k0 + 4 * kq];
    }
#pragma unroll
    for (int it = 0; it < 2; ++it) {
      const int k = kr + 32 * it;
      u32 pk[4];
#pragma unroll
      for (int j = 0; j < 4; ++j) {
        const float f0 = tf[cur][k][8 * dq + 2 * j];
        const float f1 = tf[cur][k][8 * dq + 2 * j + 1];
        pk[j] = (u32)f2bf(f0) | ((u32)f2bf(f1) << 16);
      }
      *(uint4*)&xh[(size_t)(k0 + k) * SLAB + (size_t)(b0 + bb) * 64 + 8 * dq] =
          make_uint4(pk[0], pk[1], pk[2], pk[3]);
    }
    if (bb < 7) {
#pragma unroll
      for (int i = 0; i < 4; ++i) {
        const int d = dsub + 16 * i;
        tf[cur ^ 1][4 * kq + 0][d] = rv[i].x;
        tf[cur ^ 1][4 * kq + 1][d] = rv[i].y;
        tf[cur ^ 1][4 * kq + 2][d] = rv[i].z;
        tf[cur ^ 1][4 * kq + 3][d] = rv[i].w;
      }
      __syncthreads();
    }
  }
}

// ---- K2: cov partials via MFMA; double-buffered tile, 1 barrier/sub --------
union __align__(16) K2SMem {
  u16 tile[2][64][136];   // [buf][d][b], u32-col swizzled by 4*((d>>2)&7)
  float sred[64][33];
};

__global__ __launch_bounds__(256) void k2_cov(
    const u16* __restrict__ xh, float* __restrict__ covp, float* __restrict__ Sp) {
  __shared__ K2SMem s2;
  const int part = blockIdx.x;
  const int k = blockIdx.y;
  const int t = threadIdx.x;
  const int w = t >> 6, l = t & 63;
  const int r16 = l & 15, g = l >> 4;
  const int q = t >> 3, c = t & 7;
  const u16* pk = xh + (size_t)k * SLAB;

  f32x4 hh[10];
#pragma unroll
  for (int p = 0; p < 10; ++p) hh[p] = (f32x4){0.f, 0.f, 0.f, 0.f};
  float dsums[8];
#pragma unroll
  for (int jj = 0; jj < 8; ++jj) dsums[jj] = 0.f;

  uint4 pv[4];
#define K2_LOAD(SUB)                                                           \
  {                                                                            \
    const int bbase = part * 1024 + (SUB) * 128;                               \
    _Pragma("unroll") for (int i = 0; i < 4; ++i)                              \
        pv[i] = *(const uint4*)&pk[(size_t)(bbase + 4 * q + i) * 64 + c * 8];  \
  }
#define K2_STORE(BUF)                                                          \
  {                                                                            \
    const u16* e0 = (const u16*)&pv[0];                                        \
    const u16* e1 = (const u16*)&pv[1];                                        \
    const u16* e2 = (const u16*)&pv[2];                                        \
    const u16* e3 = (const u16*)&pv[3];                                        \
    _Pragma("unroll") for (int jj = 0; jj < 8; ++jj) {                         \
      const int d = 8 * c + jj;                                                \
      const int s4 = 4 * ((d >> 2) & 7);                                       \
      const u16 v0 = e0[jj], v1 = e1[jj], v2 = e2[jj], v3 = e3[jj];            \
      dsums[jj] += (bf2f(v0) + bf2f(v1)) + (bf2f(v2) + bf2f(v3));              \
      const int col0 = (2 * q) ^ s4;                                           \
      uint2 st;                                                                \
      st.x = (u32)v0 | ((u32)v1 << 16);                                        \
      st.y = (u32)v2 | ((u32)v3 << 16);                                        \
      *(uint2*)&s2.tile[BUF][d][2 * col0] = st;                                \
    }                                                                          \
  }

  K2_LOAD(0);
  K2_STORE(0);
  __syncthreads();
  for (int sub = 0; sub < 8; ++sub) {
    const int cur = sub & 1;
    if (sub < 7) K2_LOAD(sub + 1);
    bf16x8 fr[4];
#pragma unroll
    for (int m = 0; m < 4; ++m) {
      const int d = 16 * m + r16;
      const int s4 = 4 * ((d >> 2) & 7);
      const int colb = (16 * w + 4 * g) ^ s4;
      fr[m] = *(const bf16x8*)&s2.tile[cur][d][2 * colb];
    }
#pragma unroll
    for (int m = 0; m < 4; ++m)
#pragma unroll
      for (int n = m; n < 4; ++n) {
        const int p = (m * (7 - m)) / 2 + n;
        hh[p] = __builtin_amdgcn_mfma_f32_16x16x32_bf16(fr[m], fr[n], hh[p], 0, 0, 0);
      }
    if (sub < 7) {
      K2_STORE(cur ^ 1);
      __syncthreads();
    }
  }
  float* cp = covp + ((size_t)k * 16 + part * 4 + w) * 2560;
#pragma unroll
  for (int p = 0; p < 10; ++p)
#pragma unroll
    for (int r = 0; r < 4; ++r)
      cp[p * 256 + (g * 4 + r) * 16 + r16] = hh[p][r];
  __syncthreads();
#pragma unroll
  for (int jj = 0; jj < 8; ++jj) s2.sred[8 * c + jj][q] = dsums[jj];
  __syncthreads();
  if (t < 64) {
    float s = 0.f;
#pragma unroll
    for (int q2 = 0; q2 < 32; ++q2) s += s2.sred[t][q2];
    Sp[((size_t)k * 4 + part) * 64 + t] = s;
  }
}

// ---- K3: reduce -> cov -> wave-synchronous Cholesky -> Linv + v ------------
__global__ __launch_bounds__(256) void k3_chol(
    const float* __restrict__ covp, const float* __restrict__ Sp,
    u16* __restrict__ wt, u16* __restrict__ vout) {
  __shared__ float a[64][65];
  __shared__ float mus[64];
  __shared__ float colv[64];
  const int k = blockIdx.x;
  const int tid = threadIdx.x;
  if (tid < 64) {
    float s = 0.f;
#pragma unroll
    for (int q = 0; q < 4; ++q) s += Sp[((size_t)k * 4 + q) * 64 + tid];
    mus[tid] = s * (1.f / 4096.f);
  }
  __syncthreads();
  const float* cp = covp + (size_t)k * 16 * 2560;
  for (int idx = tid; idx < 4096; idx += 256) {
    const int i = idx >> 6, j = idx & 63;
    const int i16 = i >> 4, j16 = j >> 4, r = i & 15, c = j & 15;
    int p, off;
    if (i16 <= j16) { p = (i16 * (7 - i16)) / 2 + j16; off = r * 16 + c; }
    else            { p = (j16 * (7 - j16)) / 2 + i16; off = c * 16 + r; }
    float s = 0.f;
#pragma unroll
    for (int q = 0; q < 16; ++q) s += cp[q * 2560 + p * 256 + off];
    float cv = (s - 4096.f * mus[i] * mus[j]) * (1.f / 4095.f);
    if (i == j) cv += 1e-4f;
    a[i][j] = cv;
  }
  __syncthreads();

  if (tid < 64) {
    for (int j = 0; j < 64; ++j) {
      wave_lds_fence();
      const float ljj = sqrtf(a[j][j]);
      float lij = 0.f;
      if (tid == j) a[j][j] = ljj;
      if (tid > j) {
        lij = a[tid][j] / ljj;
        a[tid][j] = lij;
        colv[tid] = lij;
      }
      wave_lds_fence();
      if (tid > j) {
        for (int e = j + 1; e <= tid; ++e) a[tid][e] -= lij * colv[e];
      }
    }
    wave_lds_fence();
    float wv[64];
#pragma unroll
    for (int i = 0; i < 64; ++i) {
      float s2 = (i == tid) ? 1.f : 0.f;
#pragma unroll
      for (int j = 0; j < i; ++j) s2 -= a[i][j] * wv[j];
      wv[i] = (i >= tid) ? s2 / a[i][i] : 0.f;
    }
    wave_lds_fence();
#pragma unroll
    for (int i = 0; i < 64; ++i) a[i][tid] = wv[i];  // a = Linv row-major
    wave_lds_fence();
    float v = 0.f;
#pragma unroll
    for (int e = 0; e < 64; ++e) v += a[tid][e] * mus[e];
    vout[(size_t)k * 64 + tid] = f2bf(v);
  }
  __syncthreads();
#pragma unroll
  for (int it = 0; it < 8; ++it) {
    const int idx = it * 256 + tid;
    const int dd = idx >> 5, ep = idx & 31;
    const u32 pk2 = (u32)f2bf(a[dd][2 * ep]) | ((u32)f2bf(a[dd][2 * ep + 1]) << 16);
    *(u32*)&wt[(size_t)k * 4096 + 2 * idx] = pk2;
  }
}

// ---- K45 v4: LDS trimmed to ~25 KB -> 5-6 blocks/CU (occupancy 2x) ---------
// grid (8 k-chunks of 32, 256 b-tiles of 16), block 256 (4 waves = d-quarters)
// xstage: 4 k-steps/rnd (16 KB dbuf); zls: 4 out-passes of 8 k (20.5 KB)
union __align__(16) SMemU {
  u16 xstage[2][4][16][64];  // [buf][k][b][d], d-chunk XOR-swizzled by b&7 (16384 B)
  u32 zls[16 * 321];         // [b]: 64 cells x 5 u32 + 1 pad (20544 B)
};

__global__ __launch_bounds__(256) void k45_solve(
    const u16* __restrict__ xh, const u16* __restrict__ wt,
    const u16* __restrict__ vin, float* __restrict__ out) {
  __shared__ SMemU sm;
  __shared__ __align__(16) u16 vsh[32][72];  // [k][d]
  const int kc0 = blockIdx.x * 32;
  const int b0 = blockIdx.y * 16;
  const int t = threadIdx.x;
  const int w = t >> 6, l = t & 63;
  const int r16 = l & 15, g = l >> 4;
  const int d0 = 16 * w + 4 * g;

  *(uint4*)&vsh[t >> 3][8 * (t & 7)] = *(const uint4*)&vin[(size_t)kc0 * 64 + t * 8];

  // staging: 4k x 16b x 64d bf16 = 8 KB/buf -> 2 uint4 per thread
  uint4 sv[2];
#pragma unroll
  for (int i = 0; i < 2; ++i) {
    const int idx = i * 256 + t;
    const int kk = idx >> 7, b = (idx >> 3) & 15, dc = idx & 7;
    sv[i] = *(const uint4*)&xh[(size_t)(kc0 + kk) * SLAB + (size_t)(b0 + b) * 64 + dc * 8];
  }
#pragma unroll
  for (int i = 0; i < 2; ++i) {
    const int idx = i * 256 + t;
    const int kk = idx >> 7, b = (idx >> 3) & 15, dc = idx & 7;
    *(uint4*)&sm.xstage[0][kk][b][(dc ^ (b & 7)) * 8] = sv[i];
  }

  bf16x8 af0[4], af1[4];
#pragma unroll
  for (int p = 0; p < 4; ++p) {
    const u16* wk = wt + (size_t)(kc0 + p) * 4096 + (16 * w + r16) * 64 + 8 * g;
    af0[p] = *(const bf16x8*)(wk);
    af1[p] = *(const bf16x8*)(wk + 32);
  }
  __syncthreads();

  u32 zr[64];

#pragma unroll
  for (int rnd = 0; rnd < 8; ++rnd) {
    if (rnd < 7) {
#pragma unroll
      for (int i = 0; i < 2; ++i) {
        const int idx = i * 256 + t;
        const int kk = idx >> 7, b = (idx >> 3) & 15, dc = idx & 7;
        sv[i] = *(const uint4*)&xh[(size_t)(kc0 + (rnd + 1) * 4 + kk) * SLAB +
                                   (size_t)(b0 + b) * 64 + dc * 8];
      }
    }
#pragma unroll
    for (int kk = 0; kk < 4; ++kk) {
      const int kidx = rnd * 4 + kk;
      const bf16x8 a0 = af0[kidx & 3];
      const bf16x8 a1 = af1[kidx & 3];
      if (kidx + 4 < 32) {
        const u16* wk = wt + (size_t)(kc0 + kidx + 4) * 4096 + (16 * w + r16) * 64 + 8 * g;
        af0[kidx & 3] = *(const bf16x8*)(wk);
        af1[kidx & 3] = *(const bf16x8*)(wk + 32);
      }
      const bf16x8 bf0 = *(const bf16x8*)&sm.xstage[rnd & 1][kk][r16][(g ^ (r16 & 7)) * 8];
      const bf16x8 bf1 = *(const bf16x8*)&sm.xstage[rnd & 1][kk][r16][((4 + g) ^ (r16 & 7)) * 8];
      f32x4 acc = (f32x4){0.f, 0.f, 0.f, 0.f};
      acc = __builtin_amdgcn_mfma_f32_16x16x32_bf16(a0, bf0, acc, 0, 0, 0);
      acc = __builtin_amdgcn_mfma_f32_16x16x32_bf16(a1, bf1, acc, 0, 0, 0);
      const uint2 vv = *(const uint2*)&vsh[kidx][d0];
      const float s0 = acc[0] - __uint_as_float(vv.x << 16);
      const float s1 = acc[1] - __uint_as_float(vv.x & 0xffff0000u);
      const float s2 = acc[2] - __uint_as_float(vv.y << 16);
      const float s3 = acc[3] - __uint_as_float(vv.y & 0xffff0000u);
      u32 plo, phi;
      asm("v_cvt_pk_bf16_f32 %0, %1, %2" : "=v"(plo) : "v"(s0), "v"(s1));
      asm("v_cvt_pk_bf16_f32 %0, %1, %2" : "=v"(phi) : "v"(s2), "v"(s3));
      zr[2 * kidx] = plo;
      zr[2 * kidx + 1] = phi;
    }
    if (rnd < 7) {
#pragma unroll
      for (int i = 0; i < 2; ++i) {
        const int idx = i * 256 + t;
        const int kk = idx >> 7, b = (idx >> 3) & 15, dc = idx & 7;
        *(uint4*)&sm.xstage[(rnd + 1) & 1][kk][b][(dc ^ (b & 7)) * 8] = sv[i];
      }
      __syncthreads();
    }
  }
  __syncthreads();  // all MFMA reads of xstage done before zls overlays it

  // out: 4 passes of 8 k; per pass: repack to k-major words, vector LDS retile
#pragma unroll
  for (int h = 0; h < 4; ++h) {
    u32 W[4][4];
#pragma unroll
    for (int r = 0; r < 4; ++r)
#pragma unroll
      for (int q2 = 0; q2 < 4; ++q2) {
        const int k2 = 8 * h + 2 * q2;
        const u32 za = zr[2 * k2 + (r >> 1)];
        const u32 zb2 = zr[2 * (k2 + 1) + (r >> 1)];
        W[r][q2] = (r & 1) ? ((za >> 16) | (zb2 & 0xffff0000u))
                           : ((za & 0xffffu) | (zb2 << 16));
      }
#pragma unroll
    for (int r = 0; r < 4; ++r) {
      u32* cp = &sm.zls[r16 * 321 + (d0 + r) * 5];
      *(uint2*)&cp[0] = make_uint2(W[r][0], W[r][1]);
      *(uint2*)&cp[2] = make_uint2(W[r][2], W[r][3]);
    }
    __syncthreads();
    // read-back: 2 lanes per (b,d) cell cover 8 k (float4 per lane)
#pragma unroll
    for (int it = 0; it < 8; ++it) {
      const int c = w * 256 + it * 32 + (l >> 1);
      const int kc = l & 1;
      const int b = c >> 6, d = c & 63;
      const uint2 zw = *(const uint2*)&sm.zls[b * 321 + d * 5 + 2 * kc];
      float4 ov;
      ov.x = __uint_as_float(zw.x << 16);
      ov.y = __uint_as_float(zw.x & 0xffff0000u);
      ov.z = __uint_as_float(zw.y << 16);
      ov.w = __uint_as_float(zw.y & 0xffff0000u);
      *(float4*)&out[(size_t)(b0 + b) * DKn + (size_t)d * Kn + kc0 + 8 * h + 4 * kc] = ov;
    }
    __syncthreads();
  }
}

extern "C" void kernel_launch(void* const* d_in, const int* in_sizes, int n_in,
                              void* d_out, int out_size, void* d_ws, size_t ws_size,
                              hipStream_t stream) {
  (void)in_sizes; (void)n_in; (void)out_size;
  const float* x = (const float*)d_in[0];
  float* out = (float*)d_out;
  char* ws = (char*)d_ws;
  const size_t XH_B = 134217728;   // u16 [256][4096][64]
  const size_t CP_B = 41943040;    // f32 [256][16][2560]
  const size_t SP_B = 262144;      // f32 [256][4][64]
  const size_t WT_B = 2097152;     // u16 [256][64][64]
  const size_t V_B  = 32768;       // u16 [256][64]
  if (ws_size < XH_B + CP_B + SP_B + WT_B + V_B) return;
  u16* xh = (u16*)ws;
  float* covp = (float*)(ws + XH_B);
  float* Sp = (float*)(ws + XH_B + CP_B);
  u16* wtb = (u16*)(ws + XH_B + CP_B + SP_B);
  u16* vb  = (u16*)(ws + XH_B + CP_B + SP_B + WT_B);

  k1_transpose<<<dim3(512, 4), 256, 0, stream>>>(x, xh);
  k2_cov<<<dim3(4, 256), 256, 0, stream>>>(xh, covp, Sp);
  k3_chol<<<dim3(256), 256, 0, stream>>>(covp, Sp, wtb, vb);
  k45_solve<<<dim3(8, 256), 256, 0, stream>>>(xh, wtb, vb, out);
}